// Round 2
// baseline (212.568 us; speedup 1.0000x reference)
//
#include <hip/hip_runtime.h>

// RBFN fused: out = sqrt(1 + max(|x|^2+|c|^2-2 x.c, 0)) @ W
// R2: GEMM1 computes S^T (m=centre,n=xrow) so phi LDS writes are b64-vector
// and GEMM2 A-frags are b128 reads; x2/c2 added in fp32 (no aug-K);
// W^T staged via coalesced column loads + one b128 write; 3 blocks/CU.

typedef __attribute__((ext_vector_type(8))) short bf16x8;
typedef __attribute__((ext_vector_type(4))) float f32x4;
typedef __attribute__((ext_vector_type(2))) unsigned int u32x2;
typedef __attribute__((ext_vector_type(4))) unsigned int u32x4;

#define N_FEAT 128
#define L_OUT  64
#define LDK    136   // sStage row stride (shorts): 272B = 17*16 ✓ aligned b128
#define LDC    40    // sPhi/sWT row stride (shorts): 80B = 5*16 ✓
#define NSB    24    // centre-splits per row-block: 32*24 = 768 blocks = 3/CU

__device__ __forceinline__ unsigned int pk2(float a, float b) {
    // two fp32 -> packed bf16 pair, round-to-nearest-even
    unsigned int ua = __builtin_bit_cast(unsigned int, a);
    unsigned int ub = __builtin_bit_cast(unsigned int, b);
    ua += 0x7FFFu + ((ua >> 16) & 1u);
    ub += 0x7FFFu + ((ub >> 16) & 1u);
    return (ua >> 16) | (ub & 0xFFFF0000u);
}

__global__ __launch_bounds__(256, 3) void rbf_fused(
    const float* __restrict__ xs, const float* __restrict__ centre,
    const float* __restrict__ weight, float* __restrict__ out) {

    __shared__ __align__(16) unsigned short sStage[32][LDK]; // x-piece / centre chunk (bf16)
    __shared__ __align__(16) unsigned short sWT[L_OUT][LDC]; // W^T chunk [l][c]
    __shared__ __align__(16) unsigned short sPhi[256][LDC];  // phi [x][c], per-wave strips
    __shared__ float sC2[32];   // |c|^2 + 1
    __shared__ float sX2[256];  // |x|^2

    const int tid  = threadIdx.x;
    const int w    = tid >> 6;
    const int lane = tid & 63;
    const int quad = lane >> 4;
    const int n16  = lane & 15;

    const int mb = blockIdx.x / NSB;
    const int sb = blockIdx.x % NSB;
    const int rowBase = mb * 256;
    const int chunk0  = (sb < 16) ? sb * 11 : sb * 10 + 16; // uneven 11/10 split of 256 chunks
    const int nCh     = (sb < 16) ? 11 : 10;

    const int sr = tid >> 3;  // staging row 0..31
    const int sq = tid & 7;   // staging 16-col group

    bf16x8 aF[4][4];          // x fragments (B-operand layout), wave's 64 rows
    f32x4  oAcc[4][4];
    #pragma unroll
    for (int xt = 0; xt < 4; ++xt)
        #pragma unroll
        for (int lt = 0; lt < 4; ++lt)
            oAcc[xt][lt] = (f32x4){0.f, 0.f, 0.f, 0.f};

    // ---- prologue: stage x (scaled by -2) piecewise; grab register fragments
    for (int p = 0; p < 8; ++p) {
        __syncthreads();
        {
            const float* g = xs + (size_t)(rowBase + p * 32 + sr) * N_FEAT + sq * 16;
            f32x4 t0 = *(const f32x4*)(g);
            f32x4 t1 = *(const f32x4*)(g + 4);
            f32x4 t2 = *(const f32x4*)(g + 8);
            f32x4 t3 = *(const f32x4*)(g + 12);
            float ss = t0.x*t0.x + t0.y*t0.y + t0.z*t0.z + t0.w*t0.w
                     + t1.x*t1.x + t1.y*t1.y + t1.z*t1.z + t1.w*t1.w
                     + t2.x*t2.x + t2.y*t2.y + t2.z*t2.z + t2.w*t2.w
                     + t3.x*t3.x + t3.y*t3.y + t3.z*t3.z + t3.w*t3.w;
            u32x4 lo = { pk2(-2.f*t0.x, -2.f*t0.y), pk2(-2.f*t0.z, -2.f*t0.w),
                         pk2(-2.f*t1.x, -2.f*t1.y), pk2(-2.f*t1.z, -2.f*t1.w) };
            u32x4 hi = { pk2(-2.f*t2.x, -2.f*t2.y), pk2(-2.f*t2.z, -2.f*t2.w),
                         pk2(-2.f*t3.x, -2.f*t3.y), pk2(-2.f*t3.z, -2.f*t3.w) };
            *(u32x4*)&sStage[sr][sq * 16]     = lo;
            *(u32x4*)&sStage[sr][sq * 16 + 8] = hi;
            ss += __shfl_xor(ss, 1);
            ss += __shfl_xor(ss, 2);
            ss += __shfl_xor(ss, 4);
            if (sq == 0) sX2[p * 32 + sr] = ss;
        }
        __syncthreads();
        if (w == (p >> 1)) {
            const int half = p & 1;
            #pragma unroll
            for (int m2 = 0; m2 < 2; ++m2)
                #pragma unroll
                for (int kc = 0; kc < 4; ++kc)
                    aF[half * 2 + m2][kc] =
                        *(const bf16x8*)&sStage[m2 * 16 + n16][kc * 32 + quad * 8];
        }
    }
    float x2v[4];
    #pragma unroll
    for (int xt = 0; xt < 4; ++xt) x2v[xt] = sX2[64 * w + xt * 16 + n16];

    // ---- main loop over 32-centre chunks
    for (int ic = 0; ic < nCh; ++ic) {
        const int n0 = (chunk0 + ic) * 32;
        __syncthreads();   // all waves done reading sStage/sWT of prev iter
        {   // stage centre chunk (scale 1)
            const float* g = centre + (size_t)(n0 + sr) * N_FEAT + sq * 16;
            f32x4 t0 = *(const f32x4*)(g);
            f32x4 t1 = *(const f32x4*)(g + 4);
            f32x4 t2 = *(const f32x4*)(g + 8);
            f32x4 t3 = *(const f32x4*)(g + 12);
            float ss = t0.x*t0.x + t0.y*t0.y + t0.z*t0.z + t0.w*t0.w
                     + t1.x*t1.x + t1.y*t1.y + t1.z*t1.z + t1.w*t1.w
                     + t2.x*t2.x + t2.y*t2.y + t2.z*t2.z + t2.w*t2.w
                     + t3.x*t3.x + t3.y*t3.y + t3.z*t3.z + t3.w*t3.w;
            u32x4 lo = { pk2(t0.x, t0.y), pk2(t0.z, t0.w),
                         pk2(t1.x, t1.y), pk2(t1.z, t1.w) };
            u32x4 hi = { pk2(t2.x, t2.y), pk2(t2.z, t2.w),
                         pk2(t3.x, t3.y), pk2(t3.z, t3.w) };
            *(u32x4*)&sStage[sr][sq * 16]     = lo;
            *(u32x4*)&sStage[sr][sq * 16 + 8] = hi;
            ss += __shfl_xor(ss, 1);
            ss += __shfl_xor(ss, 2);
            ss += __shfl_xor(ss, 4);
            if (sq == 0) sC2[sr] = ss + 1.0f;
        }
        {   // stage W^T: thread (l = tid&63, c0 = (tid>>6)*8): 8 coalesced column loads
            const int l  = tid & 63;
            const int c0 = (tid >> 6) * 8;
            const float* gw = weight + (size_t)(n0 + c0) * L_OUT + l;
            float w0 = gw[0*L_OUT], w1 = gw[1*L_OUT], w2 = gw[2*L_OUT], w3 = gw[3*L_OUT];
            float w4 = gw[4*L_OUT], w5 = gw[5*L_OUT], w6 = gw[6*L_OUT], w7 = gw[7*L_OUT];
            u32x4 pw = { pk2(w0, w1), pk2(w2, w3), pk2(w4, w5), pk2(w6, w7) };
            *(u32x4*)&sWT[l][c0] = pw;
        }
        __syncthreads();

        // GEMM1 (S^T) + phi, per 16-centre subtile
        #pragma unroll
        for (int ct = 0; ct < 2; ++ct) {
            f32x4 sAcc[4];
            #pragma unroll
            for (int xt = 0; xt < 4; ++xt) sAcc[xt] = (f32x4){0.f, 0.f, 0.f, 0.f};
            #pragma unroll
            for (int kc = 0; kc < 4; ++kc) {
                bf16x8 cA = *(const bf16x8*)&sStage[ct * 16 + n16][kc * 32 + quad * 8];
                #pragma unroll
                for (int xt = 0; xt < 4; ++xt)
                    sAcc[xt] = __builtin_amdgcn_mfma_f32_16x16x32_bf16(
                        cA, aF[xt][kc], sAcc[xt], 0, 0, 0);
            }
            f32x4 c2p1 = *(const f32x4*)&sC2[ct * 16 + quad * 4];
            #pragma unroll
            for (int xt = 0; xt < 4; ++xt) {
                float ph[4];
                #pragma unroll
                for (int r = 0; r < 4; ++r) {
                    float t = sAcc[xt][r] + x2v[xt] + c2p1[r];
                    ph[r] = __builtin_amdgcn_sqrtf(fmaxf(t, 1.0f));
                }
                u32x2 pk = { pk2(ph[0], ph[1]), pk2(ph[2], ph[3]) };
                *(u32x2*)&sPhi[64 * w + xt * 16 + n16][ct * 16 + quad * 4] = pk;
            }
        }

        // GEMM2: O[x][l] += phi @ W  (phi A-frags b128 from own strip, W^T b128)
        bf16x8 pF[4];
        #pragma unroll
        for (int xt = 0; xt < 4; ++xt)
            pF[xt] = *(const bf16x8*)&sPhi[64 * w + xt * 16 + n16][quad * 8];
        #pragma unroll
        for (int lt = 0; lt < 4; ++lt) {
            bf16x8 wF = *(const bf16x8*)&sWT[lt * 16 + n16][quad * 8];
            #pragma unroll
            for (int xt = 0; xt < 4; ++xt)
                oAcc[xt][lt] = __builtin_amdgcn_mfma_f32_16x16x32_bf16(
                    pF[xt], wF, oAcc[xt][lt], 0, 0, 0);
        }
    }

    // ---- epilogue: combine split partial sums
    float* ob = out + (size_t)(rowBase + 64 * w) * L_OUT;
    #pragma unroll
    for (int xt = 0; xt < 4; ++xt)
        #pragma unroll
        for (int lt = 0; lt < 4; ++lt)
            #pragma unroll
            for (int r = 0; r < 4; ++r)
                atomicAdd(&ob[(xt * 16 + quad * 4 + r) * L_OUT + lt * 16 + n16],
                          oAcc[xt][lt][r]);
}

extern "C" void kernel_launch(void* const* d_in, const int* in_sizes, int n_in,
                              void* d_out, int out_size, void* d_ws, size_t ws_size,
                              hipStream_t stream) {
    (void)in_sizes; (void)n_in; (void)d_ws; (void)ws_size; (void)out_size;
    const float* xs     = (const float*)d_in[0];
    const float* centre = (const float*)d_in[1];
    const float* weight = (const float*)d_in[2];
    float* out = (float*)d_out;

    hipMemsetAsync(d_out, 0, (size_t)8192 * L_OUT * sizeof(float), stream);
    rbf_fused<<<dim3(32 * NSB), dim3(256), 0, stream>>>(xs, centre, weight, out);
}

// Round 3
// 142.151 us; speedup vs baseline: 1.4954x; 1.4954x over previous
//
#include <hip/hip_runtime.h>

// RBFN fused: out = sqrt(1 + max(|x|^2+|c|^2-2 x.c, 0)) @ W
// R3: R2's micro-structure (S^T GEMM1, vector phi LDS I/O, fp32 x2/c2)
// + R1's schedule (NSB=16, 512 blocks, 2/CU, launch_bounds(256,2)) to
// eliminate the register-spill scratch traffic that killed R2.

typedef __attribute__((ext_vector_type(8))) short bf16x8;
typedef __attribute__((ext_vector_type(4))) float f32x4;
typedef __attribute__((ext_vector_type(2))) unsigned int u32x2;
typedef __attribute__((ext_vector_type(4))) unsigned int u32x4;

#define N_FEAT 128
#define L_OUT  64
#define LDK    136   // sStage row stride (shorts): 272B, b128-aligned
#define LDC    40    // sPhi/sWT row stride (shorts): 80B, b128-aligned
#define NSB    16    // centre-splits per row-block: 32*16 = 512 blocks = 2/CU
#define NCH    16    // 32-centre chunks per block (8192/16/32)

__device__ __forceinline__ unsigned int pk2(float a, float b) {
    // two fp32 -> packed bf16 pair, round-to-nearest-even
    unsigned int ua = __builtin_bit_cast(unsigned int, a);
    unsigned int ub = __builtin_bit_cast(unsigned int, b);
    ua += 0x7FFFu + ((ua >> 16) & 1u);
    ub += 0x7FFFu + ((ub >> 16) & 1u);
    return (ua >> 16) | (ub & 0xFFFF0000u);
}

__global__ __launch_bounds__(256, 2) void rbf_fused(
    const float* __restrict__ xs, const float* __restrict__ centre,
    const float* __restrict__ weight, float* __restrict__ out) {

    __shared__ __align__(16) unsigned short sStage[32][LDK]; // x-piece / centre chunk (bf16)
    __shared__ __align__(16) unsigned short sWT[L_OUT][LDC]; // W^T chunk [l][c]
    __shared__ __align__(16) unsigned short sPhi[256][LDC];  // phi [x][c], per-wave strips
    __shared__ float sC2[32];   // |c|^2 + 1
    __shared__ float sX2[256];  // |x|^2

    const int tid  = threadIdx.x;
    const int w    = tid >> 6;
    const int lane = tid & 63;
    const int quad = lane >> 4;
    const int n16  = lane & 15;

    const int mb = blockIdx.x >> 4;          // 0..31 row-block
    const int sb = blockIdx.x & (NSB - 1);   // 0..15 centre split
    const int rowBase = mb * 256;
    const int chunk0  = sb * NCH;

    const int sr = tid >> 3;  // staging row 0..31
    const int sq = tid & 7;   // staging 16-col group

    bf16x8 aF[4][4];          // x fragments (B-operand layout), wave's 64 rows
    f32x4  oAcc[4][4];
    #pragma unroll
    for (int xt = 0; xt < 4; ++xt)
        #pragma unroll
        for (int lt = 0; lt < 4; ++lt)
            oAcc[xt][lt] = (f32x4){0.f, 0.f, 0.f, 0.f};

    // ---- prologue: stage x (scaled by -2) piecewise; grab register fragments
    for (int p = 0; p < 8; ++p) {
        __syncthreads();
        {
            const float* g = xs + (size_t)(rowBase + p * 32 + sr) * N_FEAT + sq * 16;
            f32x4 t0 = *(const f32x4*)(g);
            f32x4 t1 = *(const f32x4*)(g + 4);
            f32x4 t2 = *(const f32x4*)(g + 8);
            f32x4 t3 = *(const f32x4*)(g + 12);
            float ss = t0.x*t0.x + t0.y*t0.y + t0.z*t0.z + t0.w*t0.w
                     + t1.x*t1.x + t1.y*t1.y + t1.z*t1.z + t1.w*t1.w
                     + t2.x*t2.x + t2.y*t2.y + t2.z*t2.z + t2.w*t2.w
                     + t3.x*t3.x + t3.y*t3.y + t3.z*t3.z + t3.w*t3.w;
            u32x4 lo = { pk2(-2.f*t0.x, -2.f*t0.y), pk2(-2.f*t0.z, -2.f*t0.w),
                         pk2(-2.f*t1.x, -2.f*t1.y), pk2(-2.f*t1.z, -2.f*t1.w) };
            u32x4 hi = { pk2(-2.f*t2.x, -2.f*t2.y), pk2(-2.f*t2.z, -2.f*t2.w),
                         pk2(-2.f*t3.x, -2.f*t3.y), pk2(-2.f*t3.z, -2.f*t3.w) };
            *(u32x4*)&sStage[sr][sq * 16]     = lo;
            *(u32x4*)&sStage[sr][sq * 16 + 8] = hi;
            ss += __shfl_xor(ss, 1);
            ss += __shfl_xor(ss, 2);
            ss += __shfl_xor(ss, 4);
            if (sq == 0) sX2[p * 32 + sr] = ss;
        }
        __syncthreads();
        if (w == (p >> 1)) {
            const int half = p & 1;
            #pragma unroll
            for (int m2 = 0; m2 < 2; ++m2)
                #pragma unroll
                for (int kc = 0; kc < 4; ++kc)
                    aF[half * 2 + m2][kc] =
                        *(const bf16x8*)&sStage[m2 * 16 + n16][kc * 32 + quad * 8];
        }
    }
    float x2v[4];
    #pragma unroll
    for (int xt = 0; xt < 4; ++xt) x2v[xt] = sX2[64 * w + xt * 16 + n16];

    // ---- main loop over 32-centre chunks
    for (int ic = 0; ic < NCH; ++ic) {
        const int n0 = (chunk0 + ic) * 32;
        __syncthreads();   // all waves done reading sStage/sWT of prev iter
        {   // stage centre chunk (scale 1)
            const float* g = centre + (size_t)(n0 + sr) * N_FEAT + sq * 16;
            f32x4 t0 = *(const f32x4*)(g);
            f32x4 t1 = *(const f32x4*)(g + 4);
            f32x4 t2 = *(const f32x4*)(g + 8);
            f32x4 t3 = *(const f32x4*)(g + 12);
            float ss = t0.x*t0.x + t0.y*t0.y + t0.z*t0.z + t0.w*t0.w
                     + t1.x*t1.x + t1.y*t1.y + t1.z*t1.z + t1.w*t1.w
                     + t2.x*t2.x + t2.y*t2.y + t2.z*t2.z + t2.w*t2.w
                     + t3.x*t3.x + t3.y*t3.y + t3.z*t3.z + t3.w*t3.w;
            u32x4 lo = { pk2(t0.x, t0.y), pk2(t0.z, t0.w),
                         pk2(t1.x, t1.y), pk2(t1.z, t1.w) };
            u32x4 hi = { pk2(t2.x, t2.y), pk2(t2.z, t2.w),
                         pk2(t3.x, t3.y), pk2(t3.z, t3.w) };
            *(u32x4*)&sStage[sr][sq * 16]     = lo;
            *(u32x4*)&sStage[sr][sq * 16 + 8] = hi;
            ss += __shfl_xor(ss, 1);
            ss += __shfl_xor(ss, 2);
            ss += __shfl_xor(ss, 4);
            if (sq == 0) sC2[sr] = ss + 1.0f;
        }
        {   // stage W^T: thread (l = tid&63, c0 = (tid>>6)*8): coalesced column loads
            const int l  = tid & 63;
            const int c0 = (tid >> 6) * 8;
            const float* gw = weight + (size_t)(n0 + c0) * L_OUT + l;
            float w0 = gw[0*L_OUT], w1 = gw[1*L_OUT], w2 = gw[2*L_OUT], w3 = gw[3*L_OUT];
            float w4 = gw[4*L_OUT], w5 = gw[5*L_OUT], w6 = gw[6*L_OUT], w7 = gw[7*L_OUT];
            u32x4 pw = { pk2(w0, w1), pk2(w2, w3), pk2(w4, w5), pk2(w6, w7) };
            *(u32x4*)&sWT[l][c0] = pw;
        }
        __syncthreads();

        // GEMM1 (S^T) + phi, per 16-centre subtile
        #pragma unroll
        for (int ct = 0; ct < 2; ++ct) {
            f32x4 sAcc[4];
            #pragma unroll
            for (int xt = 0; xt < 4; ++xt) sAcc[xt] = (f32x4){0.f, 0.f, 0.f, 0.f};
            #pragma unroll
            for (int kc = 0; kc < 4; ++kc) {
                bf16x8 cA = *(const bf16x8*)&sStage[ct * 16 + n16][kc * 32 + quad * 8];
                #pragma unroll
                for (int xt = 0; xt < 4; ++xt)
                    sAcc[xt] = __builtin_amdgcn_mfma_f32_16x16x32_bf16(
                        cA, aF[xt][kc], sAcc[xt], 0, 0, 0);
            }
            f32x4 c2p1 = *(const f32x4*)&sC2[ct * 16 + quad * 4];
            #pragma unroll
            for (int xt = 0; xt < 4; ++xt) {
                float ph[4];
                #pragma unroll
                for (int r = 0; r < 4; ++r) {
                    float t = sAcc[xt][r] + x2v[xt] + c2p1[r];
                    ph[r] = __builtin_amdgcn_sqrtf(fmaxf(t, 1.0f));
                }
                u32x2 pk = { pk2(ph[0], ph[1]), pk2(ph[2], ph[3]) };
                *(u32x2*)&sPhi[64 * w + xt * 16 + n16][ct * 16 + quad * 4] = pk;
            }
        }

        // GEMM2: O[x][l] += phi @ W  (phi A-frags b128 from own strip, W^T b128)
        bf16x8 pF[4];
        #pragma unroll
        for (int xt = 0; xt < 4; ++xt)
            pF[xt] = *(const bf16x8*)&sPhi[64 * w + xt * 16 + n16][quad * 8];
        #pragma unroll
        for (int lt = 0; lt < 4; ++lt) {
            bf16x8 wF = *(const bf16x8*)&sWT[lt * 16 + n16][quad * 8];
            #pragma unroll
            for (int xt = 0; xt < 4; ++xt)
                oAcc[xt][lt] = __builtin_amdgcn_mfma_f32_16x16x32_bf16(
                    pF[xt], wF, oAcc[xt][lt], 0, 0, 0);
        }
    }

    // ---- epilogue: combine split partial sums
    float* ob = out + (size_t)(rowBase + 64 * w) * L_OUT;
    #pragma unroll
    for (int xt = 0; xt < 4; ++xt)
        #pragma unroll
        for (int lt = 0; lt < 4; ++lt)
            #pragma unroll
            for (int r = 0; r < 4; ++r)
                atomicAdd(&ob[(xt * 16 + quad * 4 + r) * L_OUT + lt * 16 + n16],
                          oAcc[xt][lt][r]);
}

extern "C" void kernel_launch(void* const* d_in, const int* in_sizes, int n_in,
                              void* d_out, int out_size, void* d_ws, size_t ws_size,
                              hipStream_t stream) {
    (void)in_sizes; (void)n_in; (void)d_ws; (void)ws_size; (void)out_size;
    const float* xs     = (const float*)d_in[0];
    const float* centre = (const float*)d_in[1];
    const float* weight = (const float*)d_in[2];
    float* out = (float*)d_out;

    hipMemsetAsync(d_out, 0, (size_t)8192 * L_OUT * sizeof(float), stream);
    rbf_fused<<<dim3(32 * NSB), dim3(256), 0, stream>>>(xs, centre, weight, out);
}

// Round 4
// 112.975 us; speedup vs baseline: 1.8816x; 1.2583x over previous
//
#include <hip/hip_runtime.h>

// RBFN fused: out = sqrt(1 + max(|x|^2+|c|^2-2 x.c, 0)) @ W
// R4: (1) no global atomics -- fp32 partials to d_ws + tiny reduce kernel;
//     (2) x loaded straight into MFMA fragments (no prologue barriers);
//     (3) single barrier/iter: ping-pong LDS + register prefetch of next
//         centre/W chunk hidden under the MFMA section.

typedef __attribute__((ext_vector_type(8))) short bf16x8;
typedef __attribute__((ext_vector_type(4))) float f32x4;
typedef __attribute__((ext_vector_type(2))) unsigned int u32x2;
typedef __attribute__((ext_vector_type(4))) unsigned int u32x4;

#define N_FEAT 128
#define L_OUT  64
#define LDK    136   // sStage row stride (shorts), 272B
#define LDC    40    // sPhi/sWT row stride (shorts), 80B
#define NSB    16    // centre splits: 32 row-blocks x 16 = 512 blocks = 2/CU
#define NCH    16    // 32-centre chunks per block
#define WS_ELEMS ((size_t)NSB * 8192 * L_OUT)   // fp32 partials

__device__ __forceinline__ unsigned int pk2(float a, float b) {
    unsigned int ua = __builtin_bit_cast(unsigned int, a);
    unsigned int ub = __builtin_bit_cast(unsigned int, b);
    ua += 0x7FFFu + ((ua >> 16) & 1u);
    ub += 0x7FFFu + ((ub >> 16) & 1u);
    return (ua >> 16) | (ub & 0xFFFF0000u);
}

// MODE 0: write partials to ws. MODE 1: atomicAdd into out (fallback).
template <int MODE>
__global__ __launch_bounds__(256, 2) void rbf_fused(
    const float* __restrict__ xs, const float* __restrict__ centre,
    const float* __restrict__ weight, float* __restrict__ dst) {

    __shared__ __align__(16) unsigned short sStage[2][32][LDK];
    __shared__ __align__(16) unsigned short sWT[2][L_OUT][LDC];
    __shared__ __align__(16) unsigned short sPhi[256][LDC];
    __shared__ float sC2[2][32];

    const int tid  = threadIdx.x;
    const int w    = tid >> 6;
    const int lane = tid & 63;
    const int quad = lane >> 4;
    const int n16  = lane & 15;

    const int mb = blockIdx.x >> 4;
    const int sb = blockIdx.x & (NSB - 1);
    const int rowBase = mb * 256;
    const int chunk0  = sb * NCH;

    // ---- x fragments: direct global->register (B-operand layout), + |x|^2
    bf16x8 aF[4][4];
    float  x2v[4];
    #pragma unroll
    for (int xt = 0; xt < 4; ++xt) {
        const float* xr = xs + (size_t)(rowBase + 64 * w + xt * 16 + n16) * N_FEAT
                             + quad * 8;
        float ss = 0.f;
        #pragma unroll
        for (int kc = 0; kc < 4; ++kc) {
            f32x4 a = *(const f32x4*)(xr + kc * 32);
            f32x4 b = *(const f32x4*)(xr + kc * 32 + 4);
            ss += a.x*a.x + a.y*a.y + a.z*a.z + a.w*a.w
                + b.x*b.x + b.y*b.y + b.z*b.z + b.w*b.w;
            u32x4 p = { pk2(-2.f*a.x, -2.f*a.y), pk2(-2.f*a.z, -2.f*a.w),
                        pk2(-2.f*b.x, -2.f*b.y), pk2(-2.f*b.z, -2.f*b.w) };
            aF[xt][kc] = __builtin_bit_cast(bf16x8, p);
        }
        ss += __shfl_xor(ss, 16);
        ss += __shfl_xor(ss, 32);
        x2v[xt] = ss;   // full |x_row|^2 (sum over all 4 quads' 32 cols)
    }

    f32x4 oAcc[4][4];
    #pragma unroll
    for (int xt = 0; xt < 4; ++xt)
        #pragma unroll
        for (int lt = 0; lt < 4; ++lt)
            oAcc[xt][lt] = (f32x4){0.f, 0.f, 0.f, 0.f};

    // staging roles
    const int sr  = tid >> 3;         // centre row 0..31
    const int sq  = tid & 7;          // 16-col group
    const int wl  = tid & 63;         // W: output col l
    const int wc0 = (tid >> 6) * 8;   // W: 8 centre rows

    f32x4 pc[4];     // prefetched centre row piece (16 floats)
    float pw[8];     // prefetched W column piece

    auto loadChunk = [&](int c) {
        const float* g = centre + (size_t)(c * 32 + sr) * N_FEAT + sq * 16;
        pc[0] = *(const f32x4*)(g);
        pc[1] = *(const f32x4*)(g + 4);
        pc[2] = *(const f32x4*)(g + 8);
        pc[3] = *(const f32x4*)(g + 12);
        const float* gw = weight + (size_t)(c * 32 + wc0) * L_OUT + wl;
        #pragma unroll
        for (int i = 0; i < 8; ++i) pw[i] = gw[i * L_OUT];
    };
    auto storeChunk = [&](int b) {
        float ss = 0.f;
        #pragma unroll
        for (int i = 0; i < 4; ++i)
            ss += pc[i].x*pc[i].x + pc[i].y*pc[i].y
                + pc[i].z*pc[i].z + pc[i].w*pc[i].w;
        u32x4 lo = { pk2(pc[0].x, pc[0].y), pk2(pc[0].z, pc[0].w),
                     pk2(pc[1].x, pc[1].y), pk2(pc[1].z, pc[1].w) };
        u32x4 hi = { pk2(pc[2].x, pc[2].y), pk2(pc[2].z, pc[2].w),
                     pk2(pc[3].x, pc[3].y), pk2(pc[3].z, pc[3].w) };
        *(u32x4*)&sStage[b][sr][sq * 16]     = lo;
        *(u32x4*)&sStage[b][sr][sq * 16 + 8] = hi;
        ss += __shfl_xor(ss, 1);
        ss += __shfl_xor(ss, 2);
        ss += __shfl_xor(ss, 4);
        if (sq == 0) sC2[b][sr] = ss + 1.0f;
        u32x4 pwp = { pk2(pw[0], pw[1]), pk2(pw[2], pw[3]),
                      pk2(pw[4], pw[5]), pk2(pw[6], pw[7]) };
        *(u32x4*)&sWT[b][wl][wc0] = pwp;
    };

    loadChunk(chunk0);
    storeChunk(0);
    __syncthreads();

    for (int ic = 0; ic < NCH; ++ic) {
        const int cur = ic & 1;
        if (ic < NCH - 1) loadChunk(chunk0 + ic + 1);

        // GEMM1 (S^T: m=centre, n=x) + phi -> sPhi (wave-private strip)
        #pragma unroll
        for (int ct = 0; ct < 2; ++ct) {
            f32x4 sAcc[4];
            #pragma unroll
            for (int xt = 0; xt < 4; ++xt) sAcc[xt] = (f32x4){0.f, 0.f, 0.f, 0.f};
            #pragma unroll
            for (int kc = 0; kc < 4; ++kc) {
                bf16x8 cA = *(const bf16x8*)&sStage[cur][ct * 16 + n16][kc * 32 + quad * 8];
                #pragma unroll
                for (int xt = 0; xt < 4; ++xt)
                    sAcc[xt] = __builtin_amdgcn_mfma_f32_16x16x32_bf16(
                        cA, aF[xt][kc], sAcc[xt], 0, 0, 0);
            }
            f32x4 c2p1 = *(const f32x4*)&sC2[cur][ct * 16 + quad * 4];
            #pragma unroll
            for (int xt = 0; xt < 4; ++xt) {
                float ph[4];
                #pragma unroll
                for (int r = 0; r < 4; ++r) {
                    float t = sAcc[xt][r] + x2v[xt] + c2p1[r];
                    ph[r] = __builtin_amdgcn_sqrtf(fmaxf(t, 1.0f));
                }
                u32x2 pk = { pk2(ph[0], ph[1]), pk2(ph[2], ph[3]) };
                *(u32x2*)&sPhi[64 * w + xt * 16 + n16][ct * 16 + quad * 4] = pk;
            }
        }

        // GEMM2: oAcc += phi @ W
        bf16x8 pF[4];
        #pragma unroll
        for (int xt = 0; xt < 4; ++xt)
            pF[xt] = *(const bf16x8*)&sPhi[64 * w + xt * 16 + n16][quad * 8];
        #pragma unroll
        for (int lt = 0; lt < 4; ++lt) {
            bf16x8 wF = *(const bf16x8*)&sWT[cur][lt * 16 + n16][quad * 8];
            #pragma unroll
            for (int xt = 0; xt < 4; ++xt)
                oAcc[xt][lt] = __builtin_amdgcn_mfma_f32_16x16x32_bf16(
                    pF[xt], wF, oAcc[xt][lt], 0, 0, 0);
        }

        if (ic < NCH - 1) {
            storeChunk(cur ^ 1);
            __syncthreads();
        }
    }

    // ---- epilogue
    if (MODE == 0) {
        float* ob = dst + ((size_t)sb * 8192 + rowBase + 64 * w) * L_OUT;
        #pragma unroll
        for (int xt = 0; xt < 4; ++xt)
            #pragma unroll
            for (int lt = 0; lt < 4; ++lt)
                #pragma unroll
                for (int r = 0; r < 4; ++r)
                    ob[(xt * 16 + quad * 4 + r) * L_OUT + lt * 16 + n16] =
                        oAcc[xt][lt][r];
    } else {
        float* ob = dst + (size_t)(rowBase + 64 * w) * L_OUT;
        #pragma unroll
        for (int xt = 0; xt < 4; ++xt)
            #pragma unroll
            for (int lt = 0; lt < 4; ++lt)
                #pragma unroll
                for (int r = 0; r < 4; ++r)
                    atomicAdd(&ob[(xt * 16 + quad * 4 + r) * L_OUT + lt * 16 + n16],
                              oAcc[xt][lt][r]);
    }
}

__global__ __launch_bounds__(256) void reduce_ws(const float* __restrict__ ws,
                                                float* __restrict__ out) {
    const size_t i = ((size_t)blockIdx.x * 256 + threadIdx.x) * 4;
    f32x4 s = (f32x4){0.f, 0.f, 0.f, 0.f};
    #pragma unroll
    for (int sb = 0; sb < NSB; ++sb)
        s += *(const f32x4*)(ws + (size_t)sb * 8192 * L_OUT + i);
    *(f32x4*)(out + i) = s;
}

extern "C" void kernel_launch(void* const* d_in, const int* in_sizes, int n_in,
                              void* d_out, int out_size, void* d_ws, size_t ws_size,
                              hipStream_t stream) {
    (void)in_sizes; (void)n_in; (void)out_size;
    const float* xs     = (const float*)d_in[0];
    const float* centre = (const float*)d_in[1];
    const float* weight = (const float*)d_in[2];
    float* out = (float*)d_out;

    if (ws_size >= WS_ELEMS * sizeof(float)) {
        float* ws = (float*)d_ws;
        rbf_fused<0><<<dim3(32 * NSB), dim3(256), 0, stream>>>(xs, centre, weight, ws);
        reduce_ws<<<dim3(8192 * L_OUT / 4 / 256), dim3(256), 0, stream>>>(ws, out);
    } else {
        hipMemsetAsync(d_out, 0, (size_t)8192 * L_OUT * sizeof(float), stream);
        rbf_fused<1><<<dim3(32 * NSB), dim3(256), 0, stream>>>(xs, centre, weight, out);
    }
}

// Round 5
// 107.239 us; speedup vs baseline: 1.9822x; 1.0535x over previous
//
#include <hip/hip_runtime.h>

// RBFN fused: out = sqrt(1 + max(|x|^2+|c|^2-2 x.c, 0)) @ W
// R5: R4 structure, but 512-thread blocks (8 waves x 32-row strips) to lift
// occupancy 2 -> 4 waves/SIMD. Per-wave regs halved (aF 32, oAcc 32) so
// launch_bounds(512,4) fits without spilling. Same staging & LDS layout.

typedef __attribute__((ext_vector_type(8))) short bf16x8;
typedef __attribute__((ext_vector_type(4))) float f32x4;
typedef __attribute__((ext_vector_type(2))) unsigned int u32x2;
typedef __attribute__((ext_vector_type(4))) unsigned int u32x4;

#define N_FEAT 128
#define L_OUT  64
#define LDK    136   // sStage row stride (shorts), 272B
#define LDC    40    // sPhi/sWT row stride (shorts), 80B
#define NSB    16    // centre splits: 32 row-blocks x 16 = 512 blocks = 2/CU
#define NCH    16    // 32-centre chunks per block
#define WS_ELEMS ((size_t)NSB * 8192 * L_OUT)

__device__ __forceinline__ unsigned int pk2(float a, float b) {
    unsigned int ua = __builtin_bit_cast(unsigned int, a);
    unsigned int ub = __builtin_bit_cast(unsigned int, b);
    ua += 0x7FFFu + ((ua >> 16) & 1u);
    ub += 0x7FFFu + ((ub >> 16) & 1u);
    return (ua >> 16) | (ub & 0xFFFF0000u);
}

// MODE 0: write partials to ws. MODE 1: atomicAdd into out (fallback).
template <int MODE>
__global__ __launch_bounds__(512, 4) void rbf_fused(
    const float* __restrict__ xs, const float* __restrict__ centre,
    const float* __restrict__ weight, float* __restrict__ dst) {

    __shared__ __align__(16) unsigned short sStage[2][32][LDK];
    __shared__ __align__(16) unsigned short sWT[2][L_OUT][LDC];
    __shared__ __align__(16) unsigned short sPhi[256][LDC];   // 8 waves x 32 rows
    __shared__ float sC2[2][32];

    const int tid  = threadIdx.x;
    const int w    = tid >> 6;        // 0..7
    const int lane = tid & 63;
    const int quad = lane >> 4;
    const int n16  = lane & 15;

    const int mb = blockIdx.x >> 4;
    const int sb = blockIdx.x & (NSB - 1);
    const int rowBase = mb * 256;
    const int chunk0  = sb * NCH;

    // ---- x fragments: direct global->register (B-operand layout), + |x|^2
    bf16x8 aF[2][4];
    float  x2v[2];
    #pragma unroll
    for (int xt = 0; xt < 2; ++xt) {
        const float* xr = xs + (size_t)(rowBase + 32 * w + xt * 16 + n16) * N_FEAT
                             + quad * 8;
        float ss = 0.f;
        #pragma unroll
        for (int kc = 0; kc < 4; ++kc) {
            f32x4 a = *(const f32x4*)(xr + kc * 32);
            f32x4 b = *(const f32x4*)(xr + kc * 32 + 4);
            ss += a.x*a.x + a.y*a.y + a.z*a.z + a.w*a.w
                + b.x*b.x + b.y*b.y + b.z*b.z + b.w*b.w;
            u32x4 p = { pk2(-2.f*a.x, -2.f*a.y), pk2(-2.f*a.z, -2.f*a.w),
                        pk2(-2.f*b.x, -2.f*b.y), pk2(-2.f*b.z, -2.f*b.w) };
            aF[xt][kc] = __builtin_bit_cast(bf16x8, p);
        }
        ss += __shfl_xor(ss, 16);
        ss += __shfl_xor(ss, 32);
        x2v[xt] = ss;
    }

    f32x4 oAcc[2][4];
    #pragma unroll
    for (int xt = 0; xt < 2; ++xt)
        #pragma unroll
        for (int lt = 0; lt < 4; ++lt)
            oAcc[xt][lt] = (f32x4){0.f, 0.f, 0.f, 0.f};

    // staging roles (512 threads)
    const int sr  = tid >> 4;          // centre row 0..31
    const int sq  = tid & 15;          // 8-float group
    const int wl  = tid & 63;          // W: output col l
    const int wc0 = (tid >> 6) * 4;    // W: 4 centre rows

    f32x4 pc[2];     // prefetched centre piece (8 floats)
    float pw[4];     // prefetched W column piece

    auto loadChunk = [&](int c) {
        const float* g = centre + (size_t)(c * 32 + sr) * N_FEAT + sq * 8;
        pc[0] = *(const f32x4*)(g);
        pc[1] = *(const f32x4*)(g + 4);
        const float* gw = weight + (size_t)(c * 32 + wc0) * L_OUT + wl;
        #pragma unroll
        for (int i = 0; i < 4; ++i) pw[i] = gw[i * L_OUT];
    };
    auto storeChunk = [&](int b) {
        float ss = pc[0].x*pc[0].x + pc[0].y*pc[0].y + pc[0].z*pc[0].z + pc[0].w*pc[0].w
                 + pc[1].x*pc[1].x + pc[1].y*pc[1].y + pc[1].z*pc[1].z + pc[1].w*pc[1].w;
        u32x4 p = { pk2(pc[0].x, pc[0].y), pk2(pc[0].z, pc[0].w),
                    pk2(pc[1].x, pc[1].y), pk2(pc[1].z, pc[1].w) };
        *(u32x4*)&sStage[b][sr][sq * 8] = p;
        ss += __shfl_xor(ss, 1);
        ss += __shfl_xor(ss, 2);
        ss += __shfl_xor(ss, 4);
        ss += __shfl_xor(ss, 8);
        if (sq == 0) sC2[b][sr] = ss + 1.0f;
        u32x2 pwp = { pk2(pw[0], pw[1]), pk2(pw[2], pw[3]) };
        *(u32x2*)&sWT[b][wl][wc0] = pwp;
    };

    loadChunk(chunk0);
    storeChunk(0);
    __syncthreads();

    for (int ic = 0; ic < NCH; ++ic) {
        const int cur = ic & 1;
        if (ic < NCH - 1) loadChunk(chunk0 + ic + 1);

        // GEMM1 (S^T: m=centre, n=x) + phi -> sPhi (wave-private strip)
        #pragma unroll
        for (int ct = 0; ct < 2; ++ct) {
            f32x4 sAcc[2];
            #pragma unroll
            for (int xt = 0; xt < 2; ++xt) sAcc[xt] = (f32x4){0.f, 0.f, 0.f, 0.f};
            #pragma unroll
            for (int kc = 0; kc < 4; ++kc) {
                bf16x8 cA = *(const bf16x8*)&sStage[cur][ct * 16 + n16][kc * 32 + quad * 8];
                #pragma unroll
                for (int xt = 0; xt < 2; ++xt)
                    sAcc[xt] = __builtin_amdgcn_mfma_f32_16x16x32_bf16(
                        cA, aF[xt][kc], sAcc[xt], 0, 0, 0);
            }
            f32x4 c2p1 = *(const f32x4*)&sC2[cur][ct * 16 + quad * 4];
            #pragma unroll
            for (int xt = 0; xt < 2; ++xt) {
                float ph[4];
                #pragma unroll
                for (int r = 0; r < 4; ++r) {
                    float t = sAcc[xt][r] + x2v[xt] + c2p1[r];
                    ph[r] = __builtin_amdgcn_sqrtf(fmaxf(t, 1.0f));
                }
                u32x2 pk = { pk2(ph[0], ph[1]), pk2(ph[2], ph[3]) };
                *(u32x2*)&sPhi[32 * w + xt * 16 + n16][ct * 16 + quad * 4] = pk;
            }
        }

        // GEMM2: oAcc += phi @ W
        bf16x8 pF[2];
        #pragma unroll
        for (int xt = 0; xt < 2; ++xt)
            pF[xt] = *(const bf16x8*)&sPhi[32 * w + xt * 16 + n16][quad * 8];
        #pragma unroll
        for (int lt = 0; lt < 4; ++lt) {
            bf16x8 wF = *(const bf16x8*)&sWT[cur][lt * 16 + n16][quad * 8];
            #pragma unroll
            for (int xt = 0; xt < 2; ++xt)
                oAcc[xt][lt] = __builtin_amdgcn_mfma_f32_16x16x32_bf16(
                    pF[xt], wF, oAcc[xt][lt], 0, 0, 0);
        }

        if (ic < NCH - 1) {
            storeChunk(cur ^ 1);
            __syncthreads();
        }
    }

    // ---- epilogue
    if (MODE == 0) {
        float* ob = dst + ((size_t)sb * 8192 + rowBase + 32 * w) * L_OUT;
        #pragma unroll
        for (int xt = 0; xt < 2; ++xt)
            #pragma unroll
            for (int lt = 0; lt < 4; ++lt)
                #pragma unroll
                for (int r = 0; r < 4; ++r)
                    ob[(xt * 16 + quad * 4 + r) * L_OUT + lt * 16 + n16] =
                        oAcc[xt][lt][r];
    } else {
        float* ob = dst + (size_t)(rowBase + 32 * w) * L_OUT;
        #pragma unroll
        for (int xt = 0; xt < 2; ++xt)
            #pragma unroll
            for (int lt = 0; lt < 4; ++lt)
                #pragma unroll
                for (int r = 0; r < 4; ++r)
                    atomicAdd(&ob[(xt * 16 + quad * 4 + r) * L_OUT + lt * 16 + n16],
                              oAcc[xt][lt][r]);
    }
}

__global__ __launch_bounds__(256) void reduce_ws(const float* __restrict__ ws,
                                                float* __restrict__ out) {
    const size_t i = ((size_t)blockIdx.x * 256 + threadIdx.x) * 4;
    f32x4 s = (f32x4){0.f, 0.f, 0.f, 0.f};
    #pragma unroll
    for (int sb = 0; sb < NSB; ++sb)
        s += *(const f32x4*)(ws + (size_t)sb * 8192 * L_OUT + i);
    *(f32x4*)(out + i) = s;
}

extern "C" void kernel_launch(void* const* d_in, const int* in_sizes, int n_in,
                              void* d_out, int out_size, void* d_ws, size_t ws_size,
                              hipStream_t stream) {
    (void)in_sizes; (void)n_in; (void)out_size;
    const float* xs     = (const float*)d_in[0];
    const float* centre = (const float*)d_in[1];
    const float* weight = (const float*)d_in[2];
    float* out = (float*)d_out;

    if (ws_size >= WS_ELEMS * sizeof(float)) {
        float* ws = (float*)d_ws;
        rbf_fused<0><<<dim3(32 * NSB), dim3(512), 0, stream>>>(xs, centre, weight, ws);
        reduce_ws<<<dim3(8192 * L_OUT / 4 / 256), dim3(256), 0, stream>>>(ws, out);
    } else {
        hipMemsetAsync(d_out, 0, (size_t)8192 * L_OUT * sizeof(float), stream);
        rbf_fused<1><<<dim3(32 * NSB), dim3(512), 0, stream>>>(xs, centre, weight, out);
    }
}